// Round 4
// baseline (1440.479 us; speedup 1.0000x reference)
//
#include <hip/hip_runtime.h>
#include <stdint.h>

#define NE 50000   // entities
#define DD 128     // dim
#define RR 16      // relations
#define EE 50000   // edges per relation
#define NT 32      // node tile per block -> grid 1563
#define NTOT (RR * NE)                 // 800000 flat (r,n) keys, RELATION-major
#define SCAN_BLK 4096
#define NSCAN ((NTOT + SCAN_BLK - 1) / SCAN_BLK)   // 196

typedef short  shortx8 __attribute__((ext_vector_type(8)));
typedef short  shortx4 __attribute__((ext_vector_type(4)));
typedef float  floatx4 __attribute__((ext_vector_type(4)));

__device__ __forceinline__ unsigned short f2bf(float f) {
    unsigned u = __float_as_uint(f);
    u += 0x7fffu + ((u >> 16) & 1u);   // RNE
    return (unsigned short)(u >> 16);
}
__device__ __forceinline__ float bf2f(unsigned short h) {
    return __uint_as_float(((unsigned)h) << 16);
}

// ---- fused init: zero counts | rel_trans -> MFMA-fragment-ordered bf16 Tf | ent_emb -> bf16
// Tf: element T[r][row][k] at ((((r*8+(row>>4))*4+(k>>5))*64) + ((k>>3)&3)*16 + (row&15))*8 + (k&7)
#define ZB 782
#define TB 128
#define EB 6250
__global__ void prep_k(const float* __restrict__ rt, unsigned short* __restrict__ Tf,
                       const float4* __restrict__ emb, shortx4* __restrict__ embA,
                       int* __restrict__ counts) {
    int b = blockIdx.x, t = threadIdx.x;
    if (b < ZB) {
        int i4 = b * 256 + t;
        if (i4 < NTOT / 4) *(int4*)(counts + i4 * 4) = make_int4(0, 0, 0, 0);
    } else if (b < ZB + TB) {
        int c = (b - ZB) * 256 + t;          // chunk: 8 consecutive k of one (r,row)
        int r = c >> 11, row = (c >> 4) & 127, cb = c & 15;
        int kt = cb >> 2, qq = cb & 3, rg = row >> 4, m = row & 15;
        const float4* src = (const float4*)(rt + (size_t)c * 8);
        float4 v0 = src[0], v1 = src[1];
        shortx8 w;
        w[0] = (short)f2bf(v0.x); w[1] = (short)f2bf(v0.y);
        w[2] = (short)f2bf(v0.z); w[3] = (short)f2bf(v0.w);
        w[4] = (short)f2bf(v1.x); w[5] = (short)f2bf(v1.y);
        w[6] = (short)f2bf(v1.z); w[7] = (short)f2bf(v1.w);
        size_t idx = ((((size_t)r * 8 + rg) * 4 + kt) * 64 + qq * 16 + m) * 8;
        *(shortx8*)(Tf + idx) = w;
    } else {
        int i = (b - ZB - TB) * 256 + t;
        if (i < NE * DD / 4) {
            float4 v = emb[i];
            shortx4 w;
            w[0] = (short)f2bf(v.x); w[1] = (short)f2bf(v.y);
            w[2] = (short)f2bf(v.z); w[3] = (short)f2bf(v.w);
            embA[i] = w;
        }
    }
}

// key = r*NE + node (RELATION-major): edges for a (relation, node-tile) are one
// contiguous range -> edge-parallel gather in layer_k. Rank saved per edge so
// fill needs no atomics.
__global__ void hist_k(const int* __restrict__ erow, int* __restrict__ counts,
                       uchar4* __restrict__ rank) {
    int r  = blockIdx.y;
    int i4 = blockIdx.x * 256 + threadIdx.x;
    if (i4 < EE / 4) {
        int4 rw = *(const int4*)(erow + (size_t)r * EE + i4 * 4);
        int base0 = r * NE;
        uchar4 rk;
        rk.x = (unsigned char)atomicAdd(&counts[base0 + rw.x], 1);
        rk.y = (unsigned char)atomicAdd(&counts[base0 + rw.y], 1);
        rk.z = (unsigned char)atomicAdd(&counts[base0 + rw.z], 1);
        rk.w = (unsigned char)atomicAdd(&counts[base0 + rw.w], 1);
        rank[(size_t)r * (EE / 4) + i4] = rk;
    }
}

__global__ void scanA(const int* __restrict__ c, int* __restrict__ bsum) {
    int b = blockIdx.x, t = threadIdx.x;
    int base = b * SCAN_BLK + t * 16;
    int s = 0;
    #pragma unroll
    for (int i = 0; i < 16; i++) {
        int idx = base + i;
        if (idx < NTOT) s += c[idx];
    }
    __shared__ int sh[256];
    sh[t] = s;
    __syncthreads();
    for (int off = 128; off > 0; off >>= 1) {
        if (t < off) sh[t] += sh[t + off];
        __syncthreads();
    }
    if (t == 0) bsum[b] = sh[0];
}

// scanC derives its own block prefix from raw bsum (scanB folded in).
__global__ void scanC(const int* __restrict__ counts, int* __restrict__ rp,
                      const int* __restrict__ bsum) {
    int b = blockIdx.x, t = threadIdx.x;
    __shared__ int shb[256];
    shb[t] = (t < NSCAN) ? bsum[t] : 0;
    __syncthreads();
    for (int off = 1; off < 256; off <<= 1) {
        int add = (t >= off) ? shb[t - off] : 0;
        __syncthreads();
        shb[t] += add;
        __syncthreads();
    }
    int blockPrefix = (b > 0) ? shb[b - 1] : 0;
    int base = b * SCAN_BLK + t * 16;
    int vals[16];
    int s = 0;
    #pragma unroll
    for (int i = 0; i < 16; i++) {
        int idx = base + i;
        vals[i] = (idx < NTOT) ? counts[idx] : 0;
        s += vals[i];
    }
    __shared__ int sh[256];
    sh[t] = s;
    __syncthreads();
    for (int off = 1; off < 256; off <<= 1) {
        int add = (t >= off) ? sh[t - off] : 0;
        __syncthreads();
        sh[t] += add;
        __syncthreads();
    }
    int run = blockPrefix + sh[t] - s;
    #pragma unroll
    for (int i = 0; i < 16; i++) {
        int idx = base + i;
        if (idx < NTOT) {
            rp[idx] = run;
            run += vals[i];
            if (idx == NTOT - 1) rp[NTOT] = run;
        }
    }
}

// atomic-free placement: pos = rp[key] + saved rank.
// Edge word packs (nodeLocal<<17 | col): col < 2^17, nodeLocal = node&31 valid
// because tiles are aligned 32-node chunks.
__global__ void fill_k(const int* __restrict__ erow, const int* __restrict__ ecol,
                       const float* __restrict__ eval, const int* __restrict__ rp,
                       const uchar4* __restrict__ rank, int2* __restrict__ edges) {
    int r  = blockIdx.y;
    int i4 = blockIdx.x * 256 + threadIdx.x;
    if (i4 < EE / 4) {
        int4   rw = *(const int4*)(erow + (size_t)r * EE + i4 * 4);
        int4   cl = *(const int4*)(ecol + (size_t)r * EE + i4 * 4);
        float4 vl = *(const float4*)(eval + (size_t)r * EE + i4 * 4);
        uchar4 rk = rank[(size_t)r * (EE / 4) + i4];
        int base0 = r * NE;
        edges[rp[base0 + rw.x] + rk.x] = make_int2(((rw.x & 31) << 17) | cl.x, __float_as_int(vl.x));
        edges[rp[base0 + rw.y] + rk.y] = make_int2(((rw.y & 31) << 17) | cl.y, __float_as_int(vl.y));
        edges[rp[base0 + rw.z] + rk.z] = make_int2(((rw.z & 31) << 17) | cl.z, __float_as_int(vl.z));
        edges[rp[base0 + rw.w] + rk.w] = make_int2(((rw.w & 31) << 17) | cl.w, __float_as_int(vl.w));
    }
}

// Fused layer with EDGE-PARALLEL gather (kills the serial c>2 dependent-load tail
// that was ~10K of the ~14.8K cycles/relation in the node-parallel structure):
// per relation: zero BtF | bar | edge-parallel passes (32 edges x 8 chunk-threads,
// coalesced edge+emb loads, all rows in flight at once, ds_add_f32 accumulate)
// | bar | convert BtF->bf16 Bt (XOR-swizzled) | bar | MFMA. No barrier after MFMA
// needed (next phase touches only BtF). 3 barriers/relation, short phases.
template<bool FINAL>
__global__ __launch_bounds__(256, 6)
void layer_k(const unsigned short* __restrict__ embIn,
             const unsigned short* __restrict__ Tf,
             const int* __restrict__ rp,
             const int2* __restrict__ eg,
             unsigned short* __restrict__ embOut,
             float* __restrict__ outF)
{
    __shared__ float BtF[32 * 132];                       // 16.9 KB f32 accum, stride 132
    __shared__ __align__(16) unsigned short Bt[32 * 128]; // 8 KB bf16 staging
    __shared__ float ssred[4][32];

    const int t    = threadIdx.x;
    const int lane = t & 63;
    const int w    = t >> 6;      // 0..3: i block (x32)
    const int colq = lane & 15;
    const int q    = lane >> 4;
    const int n0   = blockIdx.x * NT;
    const int node = t >> 3;      // 0..31 (convert phase / edge slot)
    const int dgrp = t & 7;       // chunk within row
    const int nhi  = (NE - n0 < NT) ? (NE - n0) : NT;   // nodes in tile

    floatx4 acc[2][2];
    #pragma unroll
    for (int a = 0; a < 2; a++)
        #pragma unroll
        for (int c = 0; c < 2; c++)
            acc[a][c] = (floatx4){0.f, 0.f, 0.f, 0.f};

    #pragma unroll 1
    for (int r = 0; r < RR; r++) {
        // ---- zero f32 accumulator
        #pragma unroll
        for (int i = 0; i < 17; i++) {
            int idx = t + i * 256;
            if (idx < 32 * 132) BtF[idx] = 0.f;
        }
        __syncthreads();

        // ---- edge-parallel accumulate: contiguous edge range for (r, tile)
        int kb = r * NE + n0;
        int lo = rp[kb];
        int hi = rp[kb + nhi];
        int ER = hi - lo;
        #pragma unroll 1
        for (int base = 0; base < ER; base += 32) {
            int ei = base + node;          // edge slot (8 chunk-threads share one)
            bool ok = ei < ER;
            int2 E = eg[lo + ei];          // edges padded by 32 -> safe
            int   x = ok ? E.x : 0;
            float v = ok ? __int_as_float(E.y) : 0.f;
            int nl  = (x >> 17) & 31;
            int col = x & 0x1FFFF;
            const unsigned short* rowp = embIn + (size_t)col * DD + dgrp * 16;
            shortx8 c0 = *(const shortx8*)rowp;        // dims dgrp*16 .. +7
            shortx8 c1 = *(const shortx8*)(rowp + 8);  // dims dgrp*16+8 .. +15
            if (ok) {
                float* dst = &BtF[nl * 132 + dgrp * 16];
                #pragma unroll
                for (int j = 0; j < 8; j++) atomicAdd(&dst[j],     v * bf2f((unsigned short)c0[j]));
                #pragma unroll
                for (int j = 0; j < 8; j++) atomicAdd(&dst[8 + j], v * bf2f((unsigned short)c1[j]));
            }
        }
        __syncthreads();

        // ---- convert BtF -> Bt (bf16, XOR-swizzled chunk placement)
        {
            const float* src = &BtF[node * 132 + dgrp * 8];
            floatx4 f0 = *(const floatx4*)(src);
            floatx4 f1 = *(const floatx4*)(src + 4);
            floatx4 f2 = *(const floatx4*)(src + 64);
            floatx4 f3 = *(const floatx4*)(src + 68);
            shortx8 w0, w1;
            #pragma unroll
            for (int j = 0; j < 4; j++) {
                w0[j]     = (short)f2bf(f0[j]);
                w0[4 + j] = (short)f2bf(f1[j]);
                w1[j]     = (short)f2bf(f2[j]);
                w1[4 + j] = (short)f2bf(f3[j]);
            }
            int pc = (dgrp ^ node) & 7;
            *(shortx8*)&Bt[node * 128 + pc * 8] = w0;
            *(shortx8*)&Bt[node * 128 + (8 | pc) * 8] = w1;
        }
        __syncthreads();

        // ---- MFMA: A-frags from L2-resident Tf (1 kt prefetch), B from Bt
        shortx8 afN[2];
        #pragma unroll
        for (int it2 = 0; it2 < 2; it2++)
            afN[it2] = *(const shortx8*)(Tf + ((((size_t)r * 8 + (w * 2 + it2)) * 4 + 0) * 64 + lane) * 8);
        #pragma unroll 1
        for (int kt = 0; kt < 4; kt++) {
            shortx8 afC[2];
            afC[0] = afN[0]; afC[1] = afN[1];
            if (kt < 3) {
                #pragma unroll
                for (int it2 = 0; it2 < 2; it2++)
                    afN[it2] = *(const shortx8*)(Tf + ((((size_t)r * 8 + (w * 2 + it2)) * 4 + (kt + 1)) * 64 + lane) * 8);
            }
            int lc = kt * 4 + q;
            shortx8 bfr[2];
            #pragma unroll
            for (int c = 0; c < 2; c++) {
                int nl = c * 16 + colq;
                int pcr = (lc & 8) | ((lc ^ nl) & 7);
                bfr[c] = *(const shortx8*)&Bt[nl * 128 + pcr * 8];
            }
            #pragma unroll
            for (int it2 = 0; it2 < 2; it2++)
                #pragma unroll
                for (int c = 0; c < 2; c++)
                    acc[it2][c] = __builtin_amdgcn_mfma_f32_16x16x32_bf16(afC[it2], bfr[c], acc[it2][c], 0, 0, 0);
        }
        // no barrier: next phase (zero) writes BtF only; Bt protected by the
        // two barriers before the next convert.
    }

    // ---- epilogue. D: col=lane&15 -> n, row=q*4+g -> i (within 16x16 tile)
    if (!FINAL) {
        #pragma unroll
        for (int c = 0; c < 2; c++) {
            int n = n0 + c * 16 + colq;
            if (n < NE) {
                #pragma unroll
                for (int it2 = 0; it2 < 2; it2++) {
                    shortx4 wv;
                    #pragma unroll
                    for (int g = 0; g < 4; g++) {
                        float v = acc[it2][c][g];
                        v = v > 0.f ? v : 0.f;
                        wv[g] = (short)f2bf(v);
                    }
                    *(shortx4*)(embOut + ((size_t)n * DD + w * 32 + it2 * 16 + q * 4)) = wv;
                }
            }
        }
    } else {
        __syncthreads();   // Bt phase fully done before reusing LDS region (ssred separate, but cheap safety)
        #pragma unroll
        for (int c = 0; c < 2; c++) {
            float ss = 0.f;
            #pragma unroll
            for (int it2 = 0; it2 < 2; it2++)
                #pragma unroll
                for (int g = 0; g < 4; g++) {
                    float v = acc[it2][c][g];
                    v = v > 0.f ? v : 0.f;
                    acc[it2][c][g] = v;
                    ss += v * v;
                }
            ss += __shfl_xor(ss, 16, 64);   // reduce over q quads
            ss += __shfl_xor(ss, 32, 64);
            if (q == 0) ssred[w][c * 16 + colq] = ss;
        }
        __syncthreads();
        #pragma unroll
        for (int c = 0; c < 2; c++) {
            int nl = c * 16 + colq;
            float tot = ssred[0][nl] + ssred[1][nl] + ssred[2][nl] + ssred[3][nl];
            float scale = 1.f / fmaxf(sqrtf(tot), 1e-12f);
            int n = n0 + nl;
            if (n < NE) {
                #pragma unroll
                for (int it2 = 0; it2 < 2; it2++) {
                    floatx4 v4;
                    #pragma unroll
                    for (int g = 0; g < 4; g++) v4[g] = acc[it2][c][g] * scale;
                    *(floatx4*)(outF + ((size_t)n * DD + w * 32 + it2 * 16 + q * 4)) = v4;
                }
            }
        }
    }
}

static inline size_t align256(size_t x) { return (x + 255) & ~(size_t)255; }

extern "C" void kernel_launch(void* const* d_in, const int* in_sizes, int n_in,
                              void* d_out, int out_size, void* d_ws, size_t ws_size,
                              hipStream_t stream)
{
    const float* ent_emb   = (const float*)d_in[0];   // [NE, DD] fp32
    const float* rel_trans = (const float*)d_in[1];   // [RR, DD, DD] fp32
    const float* edge_val  = (const float*)d_in[2];   // [RR, EE] fp32
    const int*   edge_row  = (const int*)d_in[3];     // [RR, EE] int32
    const int*   edge_col  = (const int*)d_in[4];     // [RR, EE] int32
    float* out = (float*)d_out;                       // [NE, DD] fp32

    char* ws = (char*)d_ws;
    size_t off = 0;
    int* counts = (int*)(ws + off);  off = align256(off + (size_t)NTOT * 4);
    int* rpf    = (int*)(ws + off);  off = align256(off + ((size_t)NTOT + 1) * 4);
    int* bsum   = (int*)(ws + off);  off = align256(off + 256 * 4);
    uchar4* rank = (uchar4*)(ws + off); off = align256(off + (size_t)NTOT);
    int2* edges = (int2*)(ws + off); off = align256(off + ((size_t)NTOT + 32) * 8);  // +pad for edge-parallel overread
    unsigned short* Tf   = (unsigned short*)(ws + off); off = align256(off + (size_t)RR * DD * DD * 2);
    unsigned short* embA = (unsigned short*)(ws + off); off = align256(off + (size_t)NE * DD * 2);
    unsigned short* embB = (unsigned short*)(ws + off); off = align256(off + (size_t)NE * DD * 2);
    // total ~40 MB

    prep_k<<<ZB + TB + EB, 256, 0, stream>>>(rel_trans, Tf, (const float4*)ent_emb,
                                             (shortx4*)embA, counts);
    dim3 eg_grid((EE / 4 + 255) / 256, RR);
    hist_k<<<eg_grid, 256, 0, stream>>>(edge_row, counts, rank);
    scanA<<<NSCAN, 256, 0, stream>>>(counts, bsum);
    scanC<<<NSCAN, 256, 0, stream>>>(counts, rpf, bsum);
    fill_k<<<eg_grid, 256, 0, stream>>>(edge_row, edge_col, edge_val, rpf, rank, edges);

    int nb = (NE + NT - 1) / NT;  // 1563
    layer_k<false><<<nb, 256, 0, stream>>>(embA, Tf, rpf, edges, embB, nullptr);
    layer_k<true ><<<nb, 256, 0, stream>>>(embB, Tf, rpf, edges, nullptr, out);
}

// Round 5
// 358.262 us; speedup vs baseline: 4.0207x; 4.0207x over previous
//
#include <hip/hip_runtime.h>
#include <stdint.h>

#define NE 50000   // entities
#define DD 128     // dim
#define RR 16      // relations
#define EE 50000   // edges per relation
#define NT 64      // node tile per block
#define NTOT (RR * NE)                 // 800000 flat (n,r) keys, node-major
#define SCAN_BLK 4096
#define NSCAN ((NTOT + SCAN_BLK - 1) / SCAN_BLK)   // 196

typedef short  shortx8 __attribute__((ext_vector_type(8)));
typedef short  shortx4 __attribute__((ext_vector_type(4)));
typedef float  floatx4 __attribute__((ext_vector_type(4)));

__device__ __forceinline__ unsigned short f2bf(float f) {
    unsigned u = __float_as_uint(f);
    u += 0x7fffu + ((u >> 16) & 1u);   // RNE
    return (unsigned short)(u >> 16);
}
__device__ __forceinline__ float bf2f(unsigned short h) {
    return __uint_as_float(((unsigned)h) << 16);
}

// ---- fused init: zero counts | rel_trans -> MFMA-fragment-ordered bf16 Tf | ent_emb -> bf16
// Tf: element T[r][row][k] at ((((r*8+(row>>4))*4+(k>>5))*64) + ((k>>3)&3)*16 + (row&15))*8 + (k&7)
#define ZB 782
#define TB 128
#define EB 6250
__global__ void prep_k(const float* __restrict__ rt, unsigned short* __restrict__ Tf,
                       const float4* __restrict__ emb, shortx4* __restrict__ embA,
                       int* __restrict__ counts) {
    int b = blockIdx.x, t = threadIdx.x;
    if (b < ZB) {
        int i4 = b * 256 + t;
        if (i4 < NTOT / 4) *(int4*)(counts + i4 * 4) = make_int4(0, 0, 0, 0);
    } else if (b < ZB + TB) {
        int c = (b - ZB) * 256 + t;          // chunk: 8 consecutive k of one (r,row)
        int r = c >> 11, row = (c >> 4) & 127, cb = c & 15;
        int kt = cb >> 2, qq = cb & 3, rg = row >> 4, m = row & 15;
        const float4* src = (const float4*)(rt + (size_t)c * 8);
        float4 v0 = src[0], v1 = src[1];
        shortx8 w;
        w[0] = (short)f2bf(v0.x); w[1] = (short)f2bf(v0.y);
        w[2] = (short)f2bf(v0.z); w[3] = (short)f2bf(v0.w);
        w[4] = (short)f2bf(v1.x); w[5] = (short)f2bf(v1.y);
        w[6] = (short)f2bf(v1.z); w[7] = (short)f2bf(v1.w);
        size_t idx = ((((size_t)r * 8 + rg) * 4 + kt) * 64 + qq * 16 + m) * 8;
        *(shortx8*)(Tf + idx) = w;
    } else {
        int i = (b - ZB - TB) * 256 + t;
        if (i < NE * DD / 4) {
            float4 v = emb[i];
            shortx4 w;
            w[0] = (short)f2bf(v.x); w[1] = (short)f2bf(v.y);
            w[2] = (short)f2bf(v.z); w[3] = (short)f2bf(v.w);
            embA[i] = w;
        }
    }
}

// key = node*RR + r (node-major). Saves per-edge bucket rank so fill needs no atomics.
__global__ void hist_k(const int* __restrict__ erow, int* __restrict__ counts,
                       uchar4* __restrict__ rank) {
    int r  = blockIdx.y;
    int i4 = blockIdx.x * 256 + threadIdx.x;
    if (i4 < EE / 4) {
        int4 rw = *(const int4*)(erow + (size_t)r * EE + i4 * 4);
        uchar4 rk;
        rk.x = (unsigned char)atomicAdd(&counts[rw.x * RR + r], 1);
        rk.y = (unsigned char)atomicAdd(&counts[rw.y * RR + r], 1);
        rk.z = (unsigned char)atomicAdd(&counts[rw.z * RR + r], 1);
        rk.w = (unsigned char)atomicAdd(&counts[rw.w * RR + r], 1);
        rank[(size_t)r * (EE / 4) + i4] = rk;
    }
}

__global__ void scanA(const int* __restrict__ c, int* __restrict__ bsum) {
    int b = blockIdx.x, t = threadIdx.x;
    int base = b * SCAN_BLK + t * 16;
    int s = 0;
    #pragma unroll
    for (int i = 0; i < 16; i++) {
        int idx = base + i;
        if (idx < NTOT) s += c[idx];
    }
    __shared__ int sh[256];
    sh[t] = s;
    __syncthreads();
    for (int off = 128; off > 0; off >>= 1) {
        if (t < off) sh[t] += sh[t + off];
        __syncthreads();
    }
    if (t == 0) bsum[b] = sh[0];
}

// scanC derives its own block prefix from raw bsum (scanB folded in).
__global__ void scanC(const int* __restrict__ counts, int* __restrict__ rp,
                      const int* __restrict__ bsum) {
    int b = blockIdx.x, t = threadIdx.x;
    __shared__ int shb[256];
    shb[t] = (t < NSCAN) ? bsum[t] : 0;
    __syncthreads();
    for (int off = 1; off < 256; off <<= 1) {
        int add = (t >= off) ? shb[t - off] : 0;
        __syncthreads();
        shb[t] += add;
        __syncthreads();
    }
    int blockPrefix = (b > 0) ? shb[b - 1] : 0;
    int base = b * SCAN_BLK + t * 16;
    int vals[16];
    int s = 0;
    #pragma unroll
    for (int i = 0; i < 16; i++) {
        int idx = base + i;
        vals[i] = (idx < NTOT) ? counts[idx] : 0;
        s += vals[i];
    }
    __shared__ int sh[256];
    sh[t] = s;
    __syncthreads();
    for (int off = 1; off < 256; off <<= 1) {
        int add = (t >= off) ? sh[t - off] : 0;
        __syncthreads();
        sh[t] += add;
        __syncthreads();
    }
    int run = blockPrefix + sh[t] - s;
    #pragma unroll
    for (int i = 0; i < 16; i++) {
        int idx = base + i;
        if (idx < NTOT) {
            rp[idx] = run;
            run += vals[i];
            if (idx == NTOT - 1) rp[NTOT] = run;
        }
    }
}

// atomic-free placement: pos = rp[key] + saved rank
__global__ void fill_k(const int* __restrict__ erow, const int* __restrict__ ecol,
                       const float* __restrict__ eval, const int* __restrict__ rp,
                       const uchar4* __restrict__ rank, int2* __restrict__ edges) {
    int r  = blockIdx.y;
    int i4 = blockIdx.x * 256 + threadIdx.x;
    if (i4 < EE / 4) {
        int4   rw = *(const int4*)(erow + (size_t)r * EE + i4 * 4);
        int4   cl = *(const int4*)(ecol + (size_t)r * EE + i4 * 4);
        float4 vl = *(const float4*)(eval + (size_t)r * EE + i4 * 4);
        uchar4 rk = rank[(size_t)r * (EE / 4) + i4];
        edges[rp[rw.x * RR + r] + rk.x] = make_int2(cl.x, __float_as_int(vl.x));
        edges[rp[rw.y * RR + r] + rk.y] = make_int2(cl.y, __float_as_int(vl.y));
        edges[rp[rw.z * RR + r] + rk.z] = make_int2(cl.z, __float_as_int(vl.z));
        edges[rp[rw.w * RR + r] + rk.w] = make_int2(cl.w, __float_as_int(vl.w));
    }
}

__device__ __forceinline__ void accum_chunks(float a0[8], float a1[8], float v,
                                             shortx8 c0, shortx8 c1) {
    #pragma unroll
    for (int j = 0; j < 8; j++) {
        a0[j] = fmaf(v, bf2f((unsigned short)c0[j]), a0[j]);
        a1[j] = fmaf(v, bf2f((unsigned short)c1[j]), a1[j]);
    }
}

// Fused layer, R0 geometry (NT=64, single Bt), with the gather chain shortened:
// - 4 edges inline per (node, relation): eg[s..s+3] contiguous (1 line), all 8
//   row-chunk loads issued together -> ONE gather latency instead of up to 3
//   serial tail iterations. Serial tail only for c>4 (P=0.37%/node, ~3%/wave
//   vs 49% for the old c>2 tail).
// - e2/e3 FMA exec-mask-guarded (keeps VALU ~= R0; R1's unconditional version
//   cost +23% VALU). Row-load fallback addr = edge0's row (same line, L1 hit).
// - next relation's rp+eg prefetched before the FMA block (20 regs only; row
//   data is NOT held across barriers -- that's what spilled in R2).
// - raw lgkmcnt-only barriers (R1-validated) so the eg prefetch stays in flight.
template<bool FINAL>
__global__ __launch_bounds__(256, 3)
void layer_k(const unsigned short* __restrict__ embIn,
             const unsigned short* __restrict__ Tf,
             const int* __restrict__ rp,
             const int2* __restrict__ eg,
             unsigned short* __restrict__ embOut,
             float* __restrict__ outF)
{
    __shared__ __align__(16) unsigned short Bt[64 * 128];   // 16 KB
    __shared__ float ssred[4][64];

    const int t    = threadIdx.x;
    const int lane = t & 63;
    const int w    = t >> 6;      // 0..3: i block (x32)
    const int colq = lane & 15;
    const int q    = lane >> 4;
    const int n0   = blockIdx.x * NT;
    const int nsub = t >> 3;      // node within pass (0..31)
    const int dgrp = t & 7;       // dim chunks dgrp, dgrp+8

    floatx4 acc[2][4];
    #pragma unroll
    for (int a = 0; a < 2; a++)
        #pragma unroll
        for (int c = 0; c < 4; c++)
            acc[a][c] = (floatx4){0.f, 0.f, 0.f, 0.f};

    // ---- meta for relation 0 (chain exposed once, before the loop)
    int s_[2], c_[2];
    int2 E[2][4];
    #pragma unroll
    for (int p = 0; p < 2; p++) {
        int n = n0 + p * 32 + nsub;
        bool ok = n < NE;
        int key = (ok ? n : 0) * RR;
        int a = rp[key], b2 = rp[key + 1];
        s_[p] = a; c_[p] = ok ? (b2 - a) : 0;
        #pragma unroll
        for (int e = 0; e < 4; e++) E[p][e] = eg[a + e];   // +8 pad covers OOB
    }

    #pragma unroll 1
    for (int r = 0; r < RR; r++) {
        // ---- issue ALL row loads (2 passes x 4 edges x 2 chunks) up front
        shortx8 m[2][4][2];
        float   v[2][4];
        #pragma unroll
        for (int p = 0; p < 2; p++) {
            int col0 = c_[p] > 0 ? E[p][0].x : 0;
            int col1 = c_[p] > 1 ? E[p][1].x : col0;
            int col2 = c_[p] > 2 ? E[p][2].x : col0;
            int col3 = c_[p] > 3 ? E[p][3].x : col0;
            v[p][0] = c_[p] > 0 ? __int_as_float(E[p][0].y) : 0.f;
            v[p][1] = c_[p] > 1 ? __int_as_float(E[p][1].y) : 0.f;
            v[p][2] = __int_as_float(E[p][2].y);               // consumed only if c>2
            v[p][3] = c_[p] > 3 ? __int_as_float(E[p][3].y) : 0.f;
            const unsigned short* r0 = embIn + (size_t)col0 * DD + dgrp * 8;
            const unsigned short* r1 = embIn + (size_t)col1 * DD + dgrp * 8;
            const unsigned short* r2 = embIn + (size_t)col2 * DD + dgrp * 8;
            const unsigned short* r3 = embIn + (size_t)col3 * DD + dgrp * 8;
            m[p][0][0] = *(const shortx8*)r0;  m[p][0][1] = *(const shortx8*)(r0 + 64);
            m[p][1][0] = *(const shortx8*)r1;  m[p][1][1] = *(const shortx8*)(r1 + 64);
            m[p][2][0] = *(const shortx8*)r2;  m[p][2][1] = *(const shortx8*)(r2 + 64);
            m[p][3][0] = *(const shortx8*)r3;  m[p][3][1] = *(const shortx8*)(r3 + 64);
        }

        // ---- prefetch meta for relation r+1 (small: 20 regs; wraps harmlessly at r=15)
        int rn = (r + 1) & 15;
        int sn[2], cn[2];
        int2 En[2][4];
        #pragma unroll
        for (int p = 0; p < 2; p++) {
            int n = n0 + p * 32 + nsub;
            bool ok = n < NE;
            int key = (ok ? n : 0) * RR + rn;
            int a = rp[key], b2 = rp[key + 1];
            sn[p] = a; cn[p] = ok ? (b2 - a) : 0;
            #pragma unroll
            for (int e = 0; e < 4; e++) En[p][e] = eg[a + e];
        }

        // ---- FMA + pack -> Bt
        #pragma unroll
        for (int p = 0; p < 2; p++) {
            float a0[8], a1[8];
            #pragma unroll
            for (int j = 0; j < 8; j++) { a0[j] = 0.f; a1[j] = 0.f; }
            accum_chunks(a0, a1, v[p][0], m[p][0][0], m[p][0][1]);
            accum_chunks(a0, a1, v[p][1], m[p][1][0], m[p][1][1]);
            if (c_[p] > 2) {
                accum_chunks(a0, a1, v[p][2], m[p][2][0], m[p][2][1]);
                accum_chunks(a0, a1, v[p][3], m[p][3][0], m[p][3][1]);
            }
            if (c_[p] > 4) {
                #pragma unroll 1
                for (int k = s_[p] + 4; k < s_[p] + c_[p]; k++) {
                    int2 Et = eg[k];
                    float vt = __int_as_float(Et.y);
                    const unsigned short* rw_ = embIn + (size_t)Et.x * DD + dgrp * 8;
                    accum_chunks(a0, a1, vt, *(const shortx8*)rw_, *(const shortx8*)(rw_ + 64));
                }
            }
            int nl = p * 32 + nsub;
            shortx8 w0, w1;
            #pragma unroll
            for (int j = 0; j < 8; j++) { w0[j] = (short)f2bf(a0[j]); w1[j] = (short)f2bf(a1[j]); }
            int pc = (dgrp ^ nl) & 7;
            *(shortx8*)&Bt[nl * 128 + pc * 8] = w0;
            *(shortx8*)&Bt[nl * 128 + (8 | pc) * 8] = w1;
        }
        asm volatile("s_waitcnt lgkmcnt(0)" ::: "memory");
        __builtin_amdgcn_s_barrier();   // Bt(r) ready; eg prefetch stays in flight

        // ---- MFMA: A-frags from L2-resident Tf (1 kt prefetch), B from Bt
        shortx8 afN[2];
        #pragma unroll
        for (int it2 = 0; it2 < 2; it2++)
            afN[it2] = *(const shortx8*)(Tf + ((((size_t)r * 8 + (w * 2 + it2)) * 4 + 0) * 64 + lane) * 8);
        #pragma unroll 1
        for (int kt = 0; kt < 4; kt++) {
            shortx8 afC[2];
            afC[0] = afN[0]; afC[1] = afN[1];
            if (kt < 3) {
                #pragma unroll
                for (int it2 = 0; it2 < 2; it2++)
                    afN[it2] = *(const shortx8*)(Tf + ((((size_t)r * 8 + (w * 2 + it2)) * 4 + (kt + 1)) * 64 + lane) * 8);
            }
            int lc = kt * 4 + q;
            shortx8 bfr[4];
            #pragma unroll
            for (int c = 0; c < 4; c++) {
                int nl = c * 16 + colq;
                int pcr = (lc & 8) | ((lc ^ nl) & 7);
                bfr[c] = *(const shortx8*)&Bt[nl * 128 + pcr * 8];
            }
            #pragma unroll
            for (int it2 = 0; it2 < 2; it2++)
                #pragma unroll
                for (int c = 0; c < 4; c++)
                    acc[it2][c] = __builtin_amdgcn_mfma_f32_16x16x32_bf16(afC[it2], bfr[c], acc[it2][c], 0, 0, 0);
        }
        asm volatile("s_waitcnt lgkmcnt(0)" ::: "memory");
        __builtin_amdgcn_s_barrier();   // MFMA done with Bt

        // ---- rotate prefetched meta in
        #pragma unroll
        for (int p = 0; p < 2; p++) {
            s_[p] = sn[p]; c_[p] = cn[p];
            #pragma unroll
            for (int e = 0; e < 4; e++) E[p][e] = En[p][e];
        }
    }

    // ---- epilogue. D: col=lane&15 -> n, row=q*4+g -> i (within 16x16 tile)
    if (!FINAL) {
        #pragma unroll
        for (int c = 0; c < 4; c++) {
            int n = n0 + c * 16 + colq;
            if (n < NE) {
                #pragma unroll
                for (int it2 = 0; it2 < 2; it2++) {
                    shortx4 wv;
                    #pragma unroll
                    for (int g = 0; g < 4; g++) {
                        float vv = acc[it2][c][g];
                        vv = vv > 0.f ? vv : 0.f;
                        wv[g] = (short)f2bf(vv);
                    }
                    *(shortx4*)(embOut + ((size_t)n * DD + w * 32 + it2 * 16 + q * 4)) = wv;
                }
            }
        }
    } else {
        #pragma unroll
        for (int c = 0; c < 4; c++) {
            float ss = 0.f;
            #pragma unroll
            for (int it2 = 0; it2 < 2; it2++)
                #pragma unroll
                for (int g = 0; g < 4; g++) {
                    float vv = acc[it2][c][g];
                    vv = vv > 0.f ? vv : 0.f;
                    acc[it2][c][g] = vv;
                    ss += vv * vv;
                }
            ss += __shfl_xor(ss, 16, 64);   // reduce over q quads
            ss += __shfl_xor(ss, 32, 64);
            if (q == 0) ssred[w][c * 16 + colq] = ss;
        }
        __syncthreads();
        #pragma unroll
        for (int c = 0; c < 4; c++) {
            int nl = c * 16 + colq;
            float tot = ssred[0][nl] + ssred[1][nl] + ssred[2][nl] + ssred[3][nl];
            float scale = 1.f / fmaxf(sqrtf(tot), 1e-12f);
            int n = n0 + nl;
            if (n < NE) {
                #pragma unroll
                for (int it2 = 0; it2 < 2; it2++) {
                    floatx4 v4;
                    #pragma unroll
                    for (int g = 0; g < 4; g++) v4[g] = acc[it2][c][g] * scale;
                    *(floatx4*)(outF + ((size_t)n * DD + w * 32 + it2 * 16 + q * 4)) = v4;
                }
            }
        }
    }
}

static inline size_t align256(size_t x) { return (x + 255) & ~(size_t)255; }

extern "C" void kernel_launch(void* const* d_in, const int* in_sizes, int n_in,
                              void* d_out, int out_size, void* d_ws, size_t ws_size,
                              hipStream_t stream)
{
    const float* ent_emb   = (const float*)d_in[0];   // [NE, DD] fp32
    const float* rel_trans = (const float*)d_in[1];   // [RR, DD, DD] fp32
    const float* edge_val  = (const float*)d_in[2];   // [RR, EE] fp32
    const int*   edge_row  = (const int*)d_in[3];     // [RR, EE] int32
    const int*   edge_col  = (const int*)d_in[4];     // [RR, EE] int32
    float* out = (float*)d_out;                       // [NE, DD] fp32

    char* ws = (char*)d_ws;
    size_t off = 0;
    int* counts = (int*)(ws + off);  off = align256(off + (size_t)NTOT * 4);
    int* rpf    = (int*)(ws + off);  off = align256(off + ((size_t)NTOT + 1) * 4);
    int* bsum   = (int*)(ws + off);  off = align256(off + 256 * 4);
    uchar4* rank = (uchar4*)(ws + off); off = align256(off + (size_t)NTOT);
    int2* edges = (int2*)(ws + off); off = align256(off + ((size_t)NTOT + 8) * 8);  // +pad for 4-edge overread
    unsigned short* Tf   = (unsigned short*)(ws + off); off = align256(off + (size_t)RR * DD * DD * 2);
    unsigned short* embA = (unsigned short*)(ws + off); off = align256(off + (size_t)NE * DD * 2);
    unsigned short* embB = (unsigned short*)(ws + off); off = align256(off + (size_t)NE * DD * 2);
    // total ~40 MB

    prep_k<<<ZB + TB + EB, 256, 0, stream>>>(rel_trans, Tf, (const float4*)ent_emb,
                                             (shortx4*)embA, counts);
    dim3 eg_grid((EE / 4 + 255) / 256, RR);
    hist_k<<<eg_grid, 256, 0, stream>>>(edge_row, counts, rank);
    scanA<<<NSCAN, 256, 0, stream>>>(counts, bsum);
    scanC<<<NSCAN, 256, 0, stream>>>(counts, rpf, bsum);
    fill_k<<<eg_grid, 256, 0, stream>>>(edge_row, edge_col, edge_val, rpf, rank, edges);

    int nb = (NE + NT - 1) / NT;  // 782
    layer_k<false><<<nb, 256, 0, stream>>>(embA, Tf, rpf, edges, embB, nullptr);
    layer_k<true ><<<nb, 256, 0, stream>>>(embB, Tf, rpf, edges, nullptr, out);
}